// Round 1
// baseline (2533.789 us; speedup 1.0000x reference)
//
#include <hip/hip_runtime.h>
#include <hip/hip_bf16.h>

// Problem constants (reference): IN_DIM = HID = 64, K = 3, NCLS = 10.
// All compute fp32. Output fp32 (B*10).

// ---------------------------------------------------------------- degree
__global__ void k_deg(const int* __restrict__ src, const int* __restrict__ dst,
                      int* __restrict__ deg_s, int* __restrict__ deg_d, int E) {
  int i = blockIdx.x * blockDim.x + threadIdx.x;
  if (i < E) {
    atomicAdd(&deg_s[src[i]], 1);
    atomicAdd(&deg_d[dst[i]], 1);
  }
}

__global__ void k_norm(const int* __restrict__ deg_s, const int* __restrict__ deg_d,
                       float* __restrict__ norm_s, float* __restrict__ norm_d, int N) {
  int i = blockIdx.x * blockDim.x + threadIdx.x;
  if (i < N) {
    norm_s[i] = rsqrtf((float)max(deg_s[i], 1));
    norm_d[i] = rsqrtf((float)max(deg_d[i], 1));
  }
}

// ------------------------------------------------- (N,64) @ (64,64) GEMM
// out[v][o] = sum_k in[v][k]*norm[v]*W[k][o].  One wave per node-iteration,
// lane = output channel o.  W (16 KB) staged in LDS.
__global__ void k_gemm64(const float* __restrict__ in, const float* __restrict__ norm,
                         const float* __restrict__ W, float* __restrict__ out, int N) {
  __shared__ float Wl[4096];
  for (int i = threadIdx.x; i < 4096; i += blockDim.x) Wl[i] = W[i];
  __syncthreads();
  const int lane = threadIdx.x & 63;
  const int wavesPerBlock = blockDim.x >> 6;
  const int gw = blockIdx.x * wavesPerBlock + (threadIdx.x >> 6);
  const int nw = gridDim.x * wavesPerBlock;
  for (int v = gw; v < N; v += nw) {
    float hv = in[v * 64 + lane] * norm[v];
    float acc = 0.f;
#pragma unroll
    for (int k2 = 0; k2 < 64; ++k2)
      acc = fmaf(__shfl(hv, k2, 64), Wl[k2 * 64 + lane], acc);
    out[v * 64 + lane] = acc;
  }
}

// ------------------------------------------------- edge scatter (atomic)
// 16 threads per edge, float4 per thread: agg[dst] += m[src].
__global__ void k_scatter(const int* __restrict__ src, const int* __restrict__ dst,
                          const float* __restrict__ m, float* __restrict__ agg, int E) {
  int t = blockIdx.x * blockDim.x + threadIdx.x;
  int e = t >> 4;
  if (e >= E) return;
  int part = (t & 15) * 4;
  int s = src[e], d = dst[e];
  const float4 val = *(const float4*)(m + (size_t)s * 64 + part);
  float* ap = agg + (size_t)d * 64 + part;
  unsafeAtomicAdd(ap + 0, val.x);
  unsafeAtomicAdd(ap + 1, val.y);
  unsafeAtomicAdd(ap + 2, val.z);
  unsafeAtomicAdd(ap + 3, val.w);
}

// ------------------------------------------- epilogue: h = relu(agg*nd+b)
// One wave per node (64 channels).  Optionally emits key[v] = max_o h[v][o].
__global__ void k_epilogue(const float* __restrict__ agg, const float* __restrict__ norm_d,
                           const float* __restrict__ b, float* __restrict__ h,
                           float* __restrict__ key, int N) {
  int t = blockIdx.x * blockDim.x + threadIdx.x;
  int v = t >> 6;
  if (v >= N) return;
  int lane = t & 63;
  float val = fmaxf(fmaf(agg[t], norm_d[v], b[lane]), 0.f);
  h[t] = val;
  if (key != nullptr) {
    float mx = val;
#pragma unroll
    for (int off = 32; off; off >>= 1) mx = fmaxf(mx, __shfl_xor(mx, off, 64));
    if (lane == 0) key[v] = mx;
  }
}

// ------------------------------------------------ per-graph node ranges
__global__ void k_init_starts(int* __restrict__ gstart, int* __restrict__ gcnt,
                              int B, int N) {
  int i = blockIdx.x * blockDim.x + threadIdx.x;
  if (i < B) { gstart[i] = N; gcnt[i] = 0; }
}

__global__ void k_bounds(const int* __restrict__ gid, int* __restrict__ gstart,
                         int* __restrict__ gcnt, int N) {
  int i = blockIdx.x * blockDim.x + threadIdx.x;
  if (i < N) {
    int g = gid[i];
    atomicMin(&gstart[g], i);
    atomicAdd(&gcnt[g], 1);
  }
}

// --------------------------------------------------- top-3 keys per graph
// One wave per graph.  Order: key desc, node-index asc (matches stable
// lexsort((-key, gid))).  Keys are >= 0 (post-relu max), sentinel = -1.
__global__ void k_top3(const float* __restrict__ key, const int* __restrict__ gstart,
                       const int* __restrict__ gcnt, int* __restrict__ sel, int B) {
  const int lane = threadIdx.x & 63;
  const int g = blockIdx.x * (blockDim.x >> 6) + (threadIdx.x >> 6);
  if (g >= B) return;
  const int s = gstart[g], c = gcnt[g];
  float v0 = -1.f, v1 = -1.f, v2 = -1.f;
  int i0 = 0x7fffffff, i1 = 0x7fffffff, i2 = 0x7fffffff;
  for (int i = s + lane; i < s + c; i += 64) {
    float kv = key[i];
    if (kv > v0 || (kv == v0 && i < i0)) {
      v2 = v1; i2 = i1; v1 = v0; i1 = i0; v0 = kv; i0 = i;
    } else if (kv > v1 || (kv == v1 && i < i1)) {
      v2 = v1; i2 = i1; v1 = kv; i1 = i;
    } else if (kv > v2 || (kv == v2 && i < i2)) {
      v2 = kv; i2 = i;
    }
  }
  int ptr = 0;
  for (int r = 0; r < 3; ++r) {
    float mv = (ptr == 0) ? v0 : (ptr == 1) ? v1 : (ptr == 2) ? v2 : -1.f;
    int   mi = (ptr == 0) ? i0 : (ptr == 1) ? i1 : (ptr == 2) ? i2 : 0x7fffffff;
    float bv = mv; int bi = mi;
#pragma unroll
    for (int off = 32; off; off >>= 1) {
      float ov = __shfl_xor(bv, off, 64);
      int   oi = __shfl_xor(bi, off, 64);
      if (ov > bv || (ov == bv && oi < bi)) { bv = ov; bi = oi; }
    }
    if (bi == mi && ptr < 3) ptr++;             // winner's owner pops
    if (lane == 0) sel[g * 3 + r] = (bi == 0x7fffffff) ? -1 : bi;
  }
}

// ------------------------------------- gather selected rows + bitonic sort
// One wave per (graph, rank).  Writes p[b*192 + r*64 + lane], ascending sort.
__global__ void k_pool(const float* __restrict__ h, const int* __restrict__ sel,
                       float* __restrict__ p, int B) {
  const int lane = threadIdx.x & 63;
  const int w = blockIdx.x * (blockDim.x >> 6) + (threadIdx.x >> 6);
  if (w >= B * 3) return;
  int node = sel[w];
  float v = 0.f;
  if (node >= 0) {
    v = h[(size_t)node * 64 + lane];
    for (int k2 = 2; k2 <= 64; k2 <<= 1) {
      for (int j = k2 >> 1; j > 0; j >>= 1) {
        float o = __shfl_xor(v, j, 64);
        bool up = ((lane & k2) == 0);
        bool lower = ((lane & j) == 0);
        v = (lower == up) ? fminf(v, o) : fmaxf(v, o);
      }
    }
  }
  p[(size_t)w * 64 + lane] = v;
}

// ---------------------------------------------------------- classifier
// One 64-thread block per graph.  y[o] = relu(sum_j p[b][j]*cw[o*192+j] + cb[o]);
// out[b][c] = sum_o y[o]*Wc[o][c] + bc[c].
__global__ void k_cls(const float* __restrict__ p, const float* __restrict__ cw,
                      const float* __restrict__ cb, const float* __restrict__ Wc,
                      const float* __restrict__ bc, float* __restrict__ out, int B) {
  __shared__ float prow[192];
  const int b = blockIdx.x;
  const int lane = threadIdx.x;
  prow[lane] = p[(size_t)b * 192 + lane];
  prow[lane + 64] = p[(size_t)b * 192 + lane + 64];
  prow[lane + 128] = p[(size_t)b * 192 + lane + 128];
  __syncthreads();
  float y = cb[lane];
  for (int j = 0; j < 192; ++j) y = fmaf(prow[j], cw[lane * 192 + j], y);
  float ry = fmaxf(y, 0.f);
  for (int c = 0; c < 10; ++c) {
    float s = ry * Wc[lane * 10 + c];
#pragma unroll
    for (int off = 32; off; off >>= 1) s += __shfl_xor(s, off, 64);
    if (lane == 0) out[b * 10 + c] = s + bc[c];
  }
}

// ================================================================ launch
extern "C" void kernel_launch(void* const* d_in, const int* in_sizes, int n_in,
                              void* d_out, int out_size, void* d_ws, size_t ws_size,
                              hipStream_t stream) {
  const float* features = (const float*)d_in[0];
  const int*   esrc     = (const int*)d_in[1];
  const int*   edst     = (const int*)d_in[2];
  const int*   gid      = (const int*)d_in[3];
  // d_in[4] = num_graphs scalar (unused; B from out_size)
  const float* W1 = (const float*)d_in[5];
  const float* b1 = (const float*)d_in[6];
  const float* W2 = (const float*)d_in[7];
  const float* b2 = (const float*)d_in[8];
  const float* cw = (const float*)d_in[9];
  const float* cb = (const float*)d_in[10];
  const float* Wc = (const float*)d_in[11];
  const float* bc = (const float*)d_in[12];
  float* out = (float*)d_out;

  const int N = in_sizes[0] / 64;
  const int E = in_sizes[1];
  const int B = out_size / 10;
  const size_t N64 = (size_t)N * 64;

  // workspace carve-up (~54 MB)
  float* bufA   = (float*)d_ws;          // N*64 : m1 -> h1 -> agg2
  float* bufB   = bufA + N64;            // N*64 : agg1 -> m2 -> h2
  int*   deg_s  = (int*)(bufB + N64);    // N
  int*   deg_d  = deg_s + N;             // N
  float* norm_s = (float*)(deg_d + N);   // N
  float* norm_d = norm_s + N;            // N
  float* key    = norm_d + N;            // N
  int*   gstart = (int*)(key + N);       // B
  int*   gcnt   = gstart + B;            // B
  int*   sel    = gcnt + B;              // 3B
  float* p      = (float*)(sel + 3 * B); // 192B

  const int TB = 256;
  // degrees + norms
  hipMemsetAsync(deg_s, 0, (size_t)2 * N * sizeof(int), stream);
  k_deg<<<(E + TB - 1) / TB, TB, 0, stream>>>(esrc, edst, deg_s, deg_d, E);
  k_norm<<<(N + TB - 1) / TB, TB, 0, stream>>>(deg_s, deg_d, norm_s, norm_d, N);

  // ---- layer 1
  k_gemm64<<<1024, TB, 0, stream>>>(features, norm_s, W1, bufA, N);
  hipMemsetAsync(bufB, 0, N64 * sizeof(float), stream);
  k_scatter<<<(E * 16 + TB - 1) / TB, TB, 0, stream>>>(esrc, edst, bufA, bufB, E);
  k_epilogue<<<((int)N64 + TB - 1) / TB, TB, 0, stream>>>(bufB, norm_d, b1, bufA, nullptr, N);

  // ---- layer 2 (key = row max emitted in epilogue)
  k_gemm64<<<1024, TB, 0, stream>>>(bufA, norm_s, W2, bufB, N);
  hipMemsetAsync(bufA, 0, N64 * sizeof(float), stream);
  k_scatter<<<(E * 16 + TB - 1) / TB, TB, 0, stream>>>(esrc, edst, bufB, bufA, E);
  k_epilogue<<<((int)N64 + TB - 1) / TB, TB, 0, stream>>>(bufA, norm_d, b2, bufB, key, N);

  // ---- sort-pool
  k_init_starts<<<(B + TB - 1) / TB, TB, 0, stream>>>(gstart, gcnt, B, N);
  k_bounds<<<(N + TB - 1) / TB, TB, 0, stream>>>(gid, gstart, gcnt, N);
  k_top3<<<(B + 3) / 4, TB, 0, stream>>>(key, gstart, gcnt, sel, B);
  k_pool<<<(B * 3 + 3) / 4, TB, 0, stream>>>(bufB, sel, p, B);

  // ---- classifier
  k_cls<<<B, 64, 0, stream>>>(p, cw, cb, Wc, bc, out, B);
}

// Round 2
// 651.439 us; speedup vs baseline: 3.8895x; 3.8895x over previous
//
#include <hip/hip_runtime.h>
#include <hip/hip_bf16.h>

// Problem constants (reference): IN_DIM = HID = 64, K = 3, NCLS = 10.
// All compute fp32. Output fp32 (B*10).

// ---------------------------------------------------------------- degree
__global__ void k_deg(const int* __restrict__ src, const int* __restrict__ dst,
                      int* __restrict__ deg_s, int* __restrict__ deg_d, int E) {
  int i = blockIdx.x * blockDim.x + threadIdx.x;
  if (i < E) {
    atomicAdd(&deg_s[src[i]], 1);
    atomicAdd(&deg_d[dst[i]], 1);
  }
}

__global__ void k_norm(const int* __restrict__ deg_s, const int* __restrict__ deg_d,
                       float* __restrict__ norm_s, float* __restrict__ norm_d, int N) {
  int i = blockIdx.x * blockDim.x + threadIdx.x;
  if (i < N) {
    norm_s[i] = rsqrtf((float)max(deg_s[i], 1));
    norm_d[i] = rsqrtf((float)max(deg_d[i], 1));
  }
}

// ------------------------------------------------------------ CSR build
// scan1: per-block (2048-elem) exclusive scan of deg_d into rowptr + block sum
__global__ void k_scan1(const int* __restrict__ deg, int* __restrict__ rowptr,
                        int* __restrict__ bsum, int N) {
  __shared__ int sums[256];
  const int t = threadIdx.x;
  const int base = blockIdx.x * 2048 + t * 8;
  int loc[8];
  int tot = 0;
#pragma unroll
  for (int j = 0; j < 8; ++j) {
    int idx = base + j;
    loc[j] = tot;
    tot += (idx < N) ? deg[idx] : 0;
  }
  sums[t] = tot;
  __syncthreads();
  for (int off = 1; off < 256; off <<= 1) {
    int x = (t >= off) ? sums[t - off] : 0;
    __syncthreads();
    sums[t] += x;
    __syncthreads();
  }
  int excl = (t == 0) ? 0 : sums[t - 1];
#pragma unroll
  for (int j = 0; j < 8; ++j) {
    int idx = base + j;
    if (idx < N) rowptr[idx] = excl + loc[j];
  }
  if (t == 255) bsum[blockIdx.x] = sums[255];
}

// scan2: single wave scans block sums (nb <= 64) in place -> exclusive
__global__ void k_scan2(int* __restrict__ bsum, int nb) {
  int lane = threadIdx.x;
  int v = (lane < nb) ? bsum[lane] : 0;
  int inc = v;
#pragma unroll
  for (int off = 1; off < 64; off <<= 1) {
    int o = __shfl_up(inc, off, 64);
    if (lane >= off) inc += o;
  }
  if (lane < nb) bsum[lane] = inc - v;
}

// scan3: add block offsets, emit cursor copy for the fill
__global__ void k_scan3(int* __restrict__ rowptr, const int* __restrict__ bsum,
                        int* __restrict__ cursor, int N) {
  int i = blockIdx.x * blockDim.x + threadIdx.x;
  if (i < N) {
    int r = rowptr[i] + bsum[i >> 11];
    rowptr[i] = r;
    cursor[i] = r;
  }
}

// fill: csr_src[slot] = src, grouped by dst
__global__ void k_fill(const int* __restrict__ src, const int* __restrict__ dst,
                       int* __restrict__ cursor, int* __restrict__ csr, int E) {
  int e = blockIdx.x * blockDim.x + threadIdx.x;
  if (e < E) {
    int pos = atomicAdd(&cursor[dst[e]], 1);
    csr[pos] = src[e];
  }
}

// ------------------------------------------------- (N,64) @ (64,64) GEMM
// out[v][o] = sum_k in[v][k]*norm[v]*W[k][o].  One wave per node-iteration,
// lane = output channel o.  W (16 KB) staged in LDS.
__global__ void k_gemm64(const float* __restrict__ in, const float* __restrict__ norm,
                         const float* __restrict__ W, float* __restrict__ out, int N) {
  __shared__ float Wl[4096];
  for (int i = threadIdx.x; i < 4096; i += blockDim.x) Wl[i] = W[i];
  __syncthreads();
  const int lane = threadIdx.x & 63;
  const int wavesPerBlock = blockDim.x >> 6;
  const int gw = blockIdx.x * wavesPerBlock + (threadIdx.x >> 6);
  const int nw = gridDim.x * wavesPerBlock;
  for (int v = gw; v < N; v += nw) {
    float hv = in[v * 64 + lane] * norm[v];
    float acc = 0.f;
#pragma unroll
    for (int k2 = 0; k2 < 64; ++k2)
      acc = fmaf(__shfl(hv, k2, 64), Wl[k2 * 64 + lane], acc);
    out[v * 64 + lane] = acc;
  }
}

// ---------------------------------------- CSR gather + fused epilogue
// One wave per node.  lane = grp(edge subgroup, 2b) x quad(channel/4, 4b).
// acc[quad] = sum over in-edges of m[src][quad*4..+3]; 4 edges in flight.
// h = relu(acc*norm_d + b); key = row max (optional).
__global__ void k_gather(const float* __restrict__ m, const int* __restrict__ rowptr,
                         const int* __restrict__ deg, const float* __restrict__ norm_d,
                         const float* __restrict__ bias, const int* __restrict__ csr,
                         float* __restrict__ h, float* __restrict__ key, int N) {
  const int w = blockIdx.x * (blockDim.x >> 6) + (threadIdx.x >> 6);
  if (w >= N) return;
  const int lane = threadIdx.x & 63;
  const int quad = lane & 15;
  const int grp = lane >> 4;
  const int start = rowptr[w];
  const int cnt = deg[w];
  float4 acc = make_float4(0.f, 0.f, 0.f, 0.f);
  for (int i = grp; i < cnt; i += 4) {
    int s = csr[start + i];
    const float4 v = *(const float4*)(m + (size_t)s * 64 + quad * 4);
    acc.x += v.x; acc.y += v.y; acc.z += v.z; acc.w += v.w;
  }
  // reduce across the 4 edge-subgroups
#pragma unroll
  for (int off = 16; off <= 32; off <<= 1) {
    acc.x += __shfl_xor(acc.x, off, 64);
    acc.y += __shfl_xor(acc.y, off, 64);
    acc.z += __shfl_xor(acc.z, off, 64);
    acc.w += __shfl_xor(acc.w, off, 64);
  }
  const float nd = norm_d[w];
  const float4 bq = *(const float4*)(bias + quad * 4);
  float4 o;
  o.x = fmaxf(fmaf(acc.x, nd, bq.x), 0.f);
  o.y = fmaxf(fmaf(acc.y, nd, bq.y), 0.f);
  o.z = fmaxf(fmaf(acc.z, nd, bq.z), 0.f);
  o.w = fmaxf(fmaf(acc.w, nd, bq.w), 0.f);
  if (grp == 0) *(float4*)(h + (size_t)w * 64 + quad * 4) = o;
  if (key != nullptr) {
    float mx = fmaxf(fmaxf(o.x, o.y), fmaxf(o.z, o.w));
#pragma unroll
    for (int off = 1; off < 16; off <<= 1) mx = fmaxf(mx, __shfl_xor(mx, off, 64));
    if (lane == 0) key[w] = mx;
  }
}

// ------------------------------------------------ per-graph node ranges
__global__ void k_init_starts(int* __restrict__ gstart, int* __restrict__ gcnt,
                              int B, int N) {
  int i = blockIdx.x * blockDim.x + threadIdx.x;
  if (i < B) { gstart[i] = N; gcnt[i] = 0; }
}

__global__ void k_bounds(const int* __restrict__ gid, int* __restrict__ gstart,
                         int* __restrict__ gcnt, int N) {
  int i = blockIdx.x * blockDim.x + threadIdx.x;
  if (i < N) {
    int g = gid[i];
    atomicMin(&gstart[g], i);
    atomicAdd(&gcnt[g], 1);
  }
}

// --------------------------------------------------- top-3 keys per graph
// One wave per graph.  Order: key desc, node-index asc (matches stable
// lexsort((-key, gid))).  Keys are >= 0 (post-relu max), sentinel = -1.
__global__ void k_top3(const float* __restrict__ key, const int* __restrict__ gstart,
                       const int* __restrict__ gcnt, int* __restrict__ sel, int B) {
  const int lane = threadIdx.x & 63;
  const int g = blockIdx.x * (blockDim.x >> 6) + (threadIdx.x >> 6);
  if (g >= B) return;
  const int s = gstart[g], c = gcnt[g];
  float v0 = -1.f, v1 = -1.f, v2 = -1.f;
  int i0 = 0x7fffffff, i1 = 0x7fffffff, i2 = 0x7fffffff;
  for (int i = s + lane; i < s + c; i += 64) {
    float kv = key[i];
    if (kv > v0 || (kv == v0 && i < i0)) {
      v2 = v1; i2 = i1; v1 = v0; i1 = i0; v0 = kv; i0 = i;
    } else if (kv > v1 || (kv == v1 && i < i1)) {
      v2 = v1; i2 = i1; v1 = kv; i1 = i;
    } else if (kv > v2 || (kv == v2 && i < i2)) {
      v2 = kv; i2 = i;
    }
  }
  int ptr = 0;
  for (int r = 0; r < 3; ++r) {
    float mv = (ptr == 0) ? v0 : (ptr == 1) ? v1 : (ptr == 2) ? v2 : -1.f;
    int   mi = (ptr == 0) ? i0 : (ptr == 1) ? i1 : (ptr == 2) ? i2 : 0x7fffffff;
    float bv = mv; int bi = mi;
#pragma unroll
    for (int off = 32; off; off >>= 1) {
      float ov = __shfl_xor(bv, off, 64);
      int   oi = __shfl_xor(bi, off, 64);
      if (ov > bv || (ov == bv && oi < bi)) { bv = ov; bi = oi; }
    }
    if (bi == mi && ptr < 3) ptr++;             // winner's owner pops
    if (lane == 0) sel[g * 3 + r] = (bi == 0x7fffffff) ? -1 : bi;
  }
}

// ------------------------------------- gather selected rows + bitonic sort
// One wave per (graph, rank).  Writes p[b*192 + r*64 + lane], ascending sort.
__global__ void k_pool(const float* __restrict__ h, const int* __restrict__ sel,
                       float* __restrict__ p, int B) {
  const int lane = threadIdx.x & 63;
  const int w = blockIdx.x * (blockDim.x >> 6) + (threadIdx.x >> 6);
  if (w >= B * 3) return;
  int node = sel[w];
  float v = 0.f;
  if (node >= 0) {
    v = h[(size_t)node * 64 + lane];
    for (int k2 = 2; k2 <= 64; k2 <<= 1) {
      for (int j = k2 >> 1; j > 0; j >>= 1) {
        float o = __shfl_xor(v, j, 64);
        bool up = ((lane & k2) == 0);
        bool lower = ((lane & j) == 0);
        v = (lower == up) ? fminf(v, o) : fmaxf(v, o);
      }
    }
  }
  p[(size_t)w * 64 + lane] = v;
}

// ---------------------------------------------------------- classifier
__global__ void k_cls(const float* __restrict__ p, const float* __restrict__ cw,
                      const float* __restrict__ cb, const float* __restrict__ Wc,
                      const float* __restrict__ bc, float* __restrict__ out, int B) {
  __shared__ float prow[192];
  const int b = blockIdx.x;
  const int lane = threadIdx.x;
  prow[lane] = p[(size_t)b * 192 + lane];
  prow[lane + 64] = p[(size_t)b * 192 + lane + 64];
  prow[lane + 128] = p[(size_t)b * 192 + lane + 128];
  __syncthreads();
  float y = cb[lane];
  for (int j = 0; j < 192; ++j) y = fmaf(prow[j], cw[lane * 192 + j], y);
  float ry = fmaxf(y, 0.f);
  for (int c = 0; c < 10; ++c) {
    float s = ry * Wc[lane * 10 + c];
#pragma unroll
    for (int off = 32; off; off >>= 1) s += __shfl_xor(s, off, 64);
    if (lane == 0) out[b * 10 + c] = s + bc[c];
  }
}

// ================================================================ launch
extern "C" void kernel_launch(void* const* d_in, const int* in_sizes, int n_in,
                              void* d_out, int out_size, void* d_ws, size_t ws_size,
                              hipStream_t stream) {
  const float* features = (const float*)d_in[0];
  const int*   esrc     = (const int*)d_in[1];
  const int*   edst     = (const int*)d_in[2];
  const int*   gid      = (const int*)d_in[3];
  const float* W1 = (const float*)d_in[5];
  const float* b1 = (const float*)d_in[6];
  const float* W2 = (const float*)d_in[7];
  const float* b2 = (const float*)d_in[8];
  const float* cw = (const float*)d_in[9];
  const float* cb = (const float*)d_in[10];
  const float* Wc = (const float*)d_in[11];
  const float* bc = (const float*)d_in[12];
  float* out = (float*)d_out;

  const int N = in_sizes[0] / 64;
  const int E = in_sizes[1];
  const int B = out_size / 10;
  const size_t N64 = (size_t)N * 64;
  const int nscan = (N + 2047) / 2048;   // blocks in scan1 (49 for N=100k)

  // workspace carve-up (~57 MB)
  float* bufA   = (float*)d_ws;            // N*64 : m1 -> m2
  float* bufB   = bufA + N64;              // N*64 : h1 -> h2
  int*   deg_s  = (int*)(bufB + N64);      // N
  int*   deg_d  = deg_s + N;               // N
  float* norm_s = (float*)(deg_d + N);     // N
  float* norm_d = norm_s + N;              // N
  float* key    = norm_d + N;              // N
  int*   rowptr = (int*)(key + N);         // N
  int*   cursor = rowptr + N;              // N
  int*   csr    = cursor + N;              // E
  int*   bsum   = csr + E;                 // nscan
  int*   gstart = bsum + nscan;            // B
  int*   gcnt   = gstart + B;              // B
  int*   sel    = gcnt + B;                // 3B
  float* p      = (float*)(sel + 3 * B);   // 192B

  const int TB = 256;

  // degrees + norms + CSR
  hipMemsetAsync(deg_s, 0, (size_t)2 * N * sizeof(int), stream);
  k_deg<<<(E + TB - 1) / TB, TB, 0, stream>>>(esrc, edst, deg_s, deg_d, E);
  k_norm<<<(N + TB - 1) / TB, TB, 0, stream>>>(deg_s, deg_d, norm_s, norm_d, N);
  k_scan1<<<nscan, 256, 0, stream>>>(deg_d, rowptr, bsum, N);
  k_scan2<<<1, 64, 0, stream>>>(bsum, nscan);
  k_scan3<<<(N + TB - 1) / TB, TB, 0, stream>>>(rowptr, bsum, cursor, N);
  k_fill<<<(E + TB - 1) / TB, TB, 0, stream>>>(esrc, edst, cursor, csr, E);

  // ---- layer 1
  k_gemm64<<<1024, TB, 0, stream>>>(features, norm_s, W1, bufA, N);
  k_gather<<<(N + 3) / 4, TB, 0, stream>>>(bufA, rowptr, deg_d, norm_d, b1, csr,
                                           bufB, nullptr, N);

  // ---- layer 2 (key = row max fused)
  k_gemm64<<<1024, TB, 0, stream>>>(bufB, norm_s, W2, bufA, N);
  k_gather<<<(N + 3) / 4, TB, 0, stream>>>(bufA, rowptr, deg_d, norm_d, b2, csr,
                                           bufB, key, N);

  // ---- sort-pool
  k_init_starts<<<(B + TB - 1) / TB, TB, 0, stream>>>(gstart, gcnt, B, N);
  k_bounds<<<(N + TB - 1) / TB, TB, 0, stream>>>(gid, gstart, gcnt, N);
  k_top3<<<(B + 3) / 4, TB, 0, stream>>>(key, gstart, gcnt, sel, B);
  k_pool<<<(B * 3 + 3) / 4, TB, 0, stream>>>(bufB, sel, p, B);

  // ---- classifier
  k_cls<<<B, 64, 0, stream>>>(p, cw, cb, Wc, bc, out, B);
}

// Round 3
// 527.882 us; speedup vs baseline: 4.7999x; 1.2341x over previous
//
#include <hip/hip_runtime.h>
#include <hip/hip_bf16.h>

// Problem constants (reference): IN_DIM = HID = 64, K = 3, NCLS = 10.
// All compute fp32. Output fp32 (B*10).
//
// CSR build strategy (no global atomics anywhere):
//   PART=16128-node partitions (63 KB LDS histograms), MCH=32 edge chunks.
//   k_hist   : per-(array,partition,chunk) LDS histogram -> partial slices
//   k_degsum : sum slices -> deg_d, norm_s, norm_d
//   k_scan1/2: exclusive scan of deg_d -> rowptr (+ block sums)
//   k_scan3b : finalize rowptr; prefix-transform dst slices into per-chunk
//              absolute cursor offsets (counting sort offsets)
//   k_fill2  : per-(partition,chunk) block: LDS cursors -> csr[pos]=src

#define PART 16128
#define MCH  32

// ------------------------------------------------- histogram (LDS atomics)
// blockIdx.x = ((a*P + p)*MCH + m), a: 0=src,1=dst
__global__ void k_hist(const int* __restrict__ esrc, const int* __restrict__ edst,
                       int* __restrict__ hist, int N, int E, int P) {
  __shared__ unsigned int lds[PART];
  const int b = blockIdx.x;
  const int m = b % MCH;
  const int t2 = b / MCH;
  const int p = t2 % P;
  const int a = t2 / P;
  const int* arr = a ? edst : esrc;
  const int base = p * PART;
  const int lim = min(PART, N - base);
  for (int i = threadIdx.x; i < lim; i += blockDim.x) lds[i] = 0u;
  __syncthreads();
  const long long cb = (long long)m * E / MCH;
  const long long ce = (long long)(m + 1) * E / MCH;
  for (long long e = cb + threadIdx.x; e < ce; e += blockDim.x) {
    int v = arr[e] - base;
    if ((unsigned)v < (unsigned)lim) atomicAdd(&lds[v], 1u);
  }
  __syncthreads();
  int* slice = hist + (size_t)b * PART;
  for (int i = threadIdx.x; i < lim; i += blockDim.x) slice[i] = (int)lds[i];
}

// ------------------------------------ sum slices -> degrees + norms
__global__ void k_degsum(const int* __restrict__ hist, int* __restrict__ deg_d,
                         float* __restrict__ norm_s, float* __restrict__ norm_d,
                         int N, int P) {
  int v = blockIdx.x * blockDim.x + threadIdx.x;
  if (v >= N) return;
  int p = v / PART, loc = v % PART;
  const int* hs = hist + (size_t)p * MCH * PART + loc;
  const int* hd = hist + (size_t)(P + p) * MCH * PART + loc;
  int s = 0, d = 0;
#pragma unroll
  for (int m = 0; m < MCH; ++m) {
    s += hs[(size_t)m * PART];
    d += hd[(size_t)m * PART];
  }
  deg_d[v] = d;
  norm_s[v] = rsqrtf((float)max(s, 1));
  norm_d[v] = rsqrtf((float)max(d, 1));
}

// ------------------------------------------------------------ CSR scan
// scan1: per-block (2048-elem) exclusive scan of deg_d into rowptr + block sum
__global__ void k_scan1(const int* __restrict__ deg, int* __restrict__ rowptr,
                        int* __restrict__ bsum, int N) {
  __shared__ int sums[256];
  const int t = threadIdx.x;
  const int base = blockIdx.x * 2048 + t * 8;
  int loc[8];
  int tot = 0;
#pragma unroll
  for (int j = 0; j < 8; ++j) {
    int idx = base + j;
    loc[j] = tot;
    tot += (idx < N) ? deg[idx] : 0;
  }
  sums[t] = tot;
  __syncthreads();
  for (int off = 1; off < 256; off <<= 1) {
    int x = (t >= off) ? sums[t - off] : 0;
    __syncthreads();
    sums[t] += x;
    __syncthreads();
  }
  int excl = (t == 0) ? 0 : sums[t - 1];
#pragma unroll
  for (int j = 0; j < 8; ++j) {
    int idx = base + j;
    if (idx < N) rowptr[idx] = excl + loc[j];
  }
  if (t == 255) bsum[blockIdx.x] = sums[255];
}

// scan2: single wave scans block sums (nb <= 64) in place -> exclusive
__global__ void k_scan2(int* __restrict__ bsum, int nb) {
  int lane = threadIdx.x;
  int v = (lane < nb) ? bsum[lane] : 0;
  int inc = v;
#pragma unroll
  for (int off = 1; off < 64; off <<= 1) {
    int o = __shfl_up(inc, off, 64);
    if (lane >= off) inc += o;
  }
  if (lane < nb) bsum[lane] = inc - v;
}

// scan3b: finalize rowptr; transform dst hist slices into per-chunk cursors
__global__ void k_scan3b(int* __restrict__ rowptr, const int* __restrict__ bsum,
                         int* __restrict__ hist, int N, int P) {
  int v = blockIdx.x * blockDim.x + threadIdx.x;
  if (v >= N) return;
  int r = rowptr[v] + bsum[v >> 11];
  rowptr[v] = r;
  int p = v / PART, loc = v % PART;
  int* hd = hist + (size_t)(P + p) * MCH * PART + loc;
  int run = r;
#pragma unroll
  for (int m = 0; m < MCH; ++m) {
    int t = hd[(size_t)m * PART];
    hd[(size_t)m * PART] = run;
    run += t;
  }
}

// ----------------------------------------- fill (LDS cursors, no atomics)
// blockIdx.x = p*MCH + m
__global__ void k_fill2(const int* __restrict__ esrc, const int* __restrict__ edst,
                        const int* __restrict__ hist, int* __restrict__ csr,
                        int N, int E, int P) {
  __shared__ int cur[PART];
  const int b = blockIdx.x;
  const int m = b % MCH;
  const int p = b / MCH;
  const int base = p * PART;
  const int lim = min(PART, N - base);
  const int* slice = hist + ((size_t)(P + p) * MCH + m) * PART;
  for (int i = threadIdx.x; i < lim; i += blockDim.x) cur[i] = slice[i];
  __syncthreads();
  const long long cb = (long long)m * E / MCH;
  const long long ce = (long long)(m + 1) * E / MCH;
  for (long long e = cb + threadIdx.x; e < ce; e += blockDim.x) {
    int d = edst[e] - base;
    if ((unsigned)d < (unsigned)lim) {
      int pos = atomicAdd(&cur[d], 1);
      csr[pos] = esrc[e];
    }
  }
}

// ------------------------------------------------- (N,64) @ (64,64) GEMM
__global__ void k_gemm64(const float* __restrict__ in, const float* __restrict__ norm,
                         const float* __restrict__ W, float* __restrict__ out, int N) {
  __shared__ float Wl[4096];
  for (int i = threadIdx.x; i < 4096; i += blockDim.x) Wl[i] = W[i];
  __syncthreads();
  const int lane = threadIdx.x & 63;
  const int wavesPerBlock = blockDim.x >> 6;
  const int gw = blockIdx.x * wavesPerBlock + (threadIdx.x >> 6);
  const int nw = gridDim.x * wavesPerBlock;
  for (int v = gw; v < N; v += nw) {
    float hv = in[v * 64 + lane] * norm[v];
    float acc = 0.f;
#pragma unroll
    for (int k2 = 0; k2 < 64; ++k2)
      acc = fmaf(__shfl(hv, k2, 64), Wl[k2 * 64 + lane], acc);
    out[v * 64 + lane] = acc;
  }
}

// ---------------------------------------- CSR gather + fused epilogue
__global__ void k_gather(const float* __restrict__ m, const int* __restrict__ rowptr,
                         const int* __restrict__ deg, const float* __restrict__ norm_d,
                         const float* __restrict__ bias, const int* __restrict__ csr,
                         float* __restrict__ h, float* __restrict__ key, int N) {
  const int w = blockIdx.x * (blockDim.x >> 6) + (threadIdx.x >> 6);
  if (w >= N) return;
  const int lane = threadIdx.x & 63;
  const int quad = lane & 15;
  const int grp = lane >> 4;
  const int start = rowptr[w];
  const int cnt = deg[w];
  float4 acc = make_float4(0.f, 0.f, 0.f, 0.f);
  for (int i = grp; i < cnt; i += 4) {
    int s = csr[start + i];
    const float4 v = *(const float4*)(m + (size_t)s * 64 + quad * 4);
    acc.x += v.x; acc.y += v.y; acc.z += v.z; acc.w += v.w;
  }
#pragma unroll
  for (int off = 16; off <= 32; off <<= 1) {
    acc.x += __shfl_xor(acc.x, off, 64);
    acc.y += __shfl_xor(acc.y, off, 64);
    acc.z += __shfl_xor(acc.z, off, 64);
    acc.w += __shfl_xor(acc.w, off, 64);
  }
  const float nd = norm_d[w];
  const float4 bq = *(const float4*)(bias + quad * 4);
  float4 o;
  o.x = fmaxf(fmaf(acc.x, nd, bq.x), 0.f);
  o.y = fmaxf(fmaf(acc.y, nd, bq.y), 0.f);
  o.z = fmaxf(fmaf(acc.z, nd, bq.z), 0.f);
  o.w = fmaxf(fmaf(acc.w, nd, bq.w), 0.f);
  if (grp == 0) *(float4*)(h + (size_t)w * 64 + quad * 4) = o;
  if (key != nullptr) {
    float mx = fmaxf(fmaxf(o.x, o.y), fmaxf(o.z, o.w));
#pragma unroll
    for (int off = 1; off < 16; off <<= 1) mx = fmaxf(mx, __shfl_xor(mx, off, 64));
    if (lane == 0) key[w] = mx;
  }
}

// ------------------------------------------- per-graph ranges (no atomics)
__global__ void k_init_starts(int* __restrict__ gstart, int B, int N) {
  int i = blockIdx.x * blockDim.x + threadIdx.x;
  if (i < B) gstart[i] = N;
}

// gid is sorted: starts are boundary positions
__global__ void k_bstart(const int* __restrict__ gid, int* __restrict__ gstart, int N) {
  int i = blockIdx.x * blockDim.x + threadIdx.x;
  if (i >= N) return;
  int g = gid[i];
  if (i == 0 || gid[i - 1] != g) gstart[g] = i;
}

// one block of 512: gcnt[g] = next start - start via LDS suffix-min (B<=512)
__global__ void k_bfin(const int* __restrict__ gstart, int* __restrict__ gcnt,
                       int B, int N) {
  __shared__ int sm[512];
  const int g = threadIdx.x;
  sm[g] = (g < B) ? gstart[g] : 0x7fffffff;
  __syncthreads();
  for (int off = 1; off < 512; off <<= 1) {
    int x = (g + off < 512) ? sm[g + off] : 0x7fffffff;
    __syncthreads();
    sm[g] = min(sm[g], x);
    __syncthreads();
  }
  if (g < B) {
    int gs = gstart[g];
    int ns = (g + 1 < 512) ? min(sm[g + 1], N) : N;
    gcnt[g] = (gs < N) ? (ns - gs) : 0;
  }
}

// --------------------------------------------------- top-3 keys per graph
__global__ void k_top3(const float* __restrict__ key, const int* __restrict__ gstart,
                       const int* __restrict__ gcnt, int* __restrict__ sel, int B) {
  const int lane = threadIdx.x & 63;
  const int g = blockIdx.x * (blockDim.x >> 6) + (threadIdx.x >> 6);
  if (g >= B) return;
  const int s = gstart[g], c = gcnt[g];
  float v0 = -1.f, v1 = -1.f, v2 = -1.f;
  int i0 = 0x7fffffff, i1 = 0x7fffffff, i2 = 0x7fffffff;
  for (int i = s + lane; i < s + c; i += 64) {
    float kv = key[i];
    if (kv > v0 || (kv == v0 && i < i0)) {
      v2 = v1; i2 = i1; v1 = v0; i1 = i0; v0 = kv; i0 = i;
    } else if (kv > v1 || (kv == v1 && i < i1)) {
      v2 = v1; i2 = i1; v1 = kv; i1 = i;
    } else if (kv > v2 || (kv == v2 && i < i2)) {
      v2 = kv; i2 = i;
    }
  }
  int ptr = 0;
  for (int r = 0; r < 3; ++r) {
    float mv = (ptr == 0) ? v0 : (ptr == 1) ? v1 : (ptr == 2) ? v2 : -1.f;
    int   mi = (ptr == 0) ? i0 : (ptr == 1) ? i1 : (ptr == 2) ? i2 : 0x7fffffff;
    float bv = mv; int bi = mi;
#pragma unroll
    for (int off = 32; off; off >>= 1) {
      float ov = __shfl_xor(bv, off, 64);
      int   oi = __shfl_xor(bi, off, 64);
      if (ov > bv || (ov == bv && oi < bi)) { bv = ov; bi = oi; }
    }
    if (bi == mi && ptr < 3) ptr++;             // winner's owner pops
    if (lane == 0) sel[g * 3 + r] = (bi == 0x7fffffff) ? -1 : bi;
  }
}

// ------------------------------------- gather selected rows + bitonic sort
__global__ void k_pool(const float* __restrict__ h, const int* __restrict__ sel,
                       float* __restrict__ p, int B) {
  const int lane = threadIdx.x & 63;
  const int w = blockIdx.x * (blockDim.x >> 6) + (threadIdx.x >> 6);
  if (w >= B * 3) return;
  int node = sel[w];
  float v = 0.f;
  if (node >= 0) {
    v = h[(size_t)node * 64 + lane];
    for (int k2 = 2; k2 <= 64; k2 <<= 1) {
      for (int j = k2 >> 1; j > 0; j >>= 1) {
        float o = __shfl_xor(v, j, 64);
        bool up = ((lane & k2) == 0);
        bool lower = ((lane & j) == 0);
        v = (lower == up) ? fminf(v, o) : fmaxf(v, o);
      }
    }
  }
  p[(size_t)w * 64 + lane] = v;
}

// ---------------------------------------------------------- classifier
__global__ void k_cls(const float* __restrict__ p, const float* __restrict__ cw,
                      const float* __restrict__ cb, const float* __restrict__ Wc,
                      const float* __restrict__ bc, float* __restrict__ out, int B) {
  __shared__ float prow[192];
  const int b = blockIdx.x;
  const int lane = threadIdx.x;
  prow[lane] = p[(size_t)b * 192 + lane];
  prow[lane + 64] = p[(size_t)b * 192 + lane + 64];
  prow[lane + 128] = p[(size_t)b * 192 + lane + 128];
  __syncthreads();
  float y = cb[lane];
  for (int j = 0; j < 192; ++j) y = fmaf(prow[j], cw[lane * 192 + j], y);
  float ry = fmaxf(y, 0.f);
  for (int c = 0; c < 10; ++c) {
    float s = ry * Wc[lane * 10 + c];
#pragma unroll
    for (int off = 32; off; off >>= 1) s += __shfl_xor(s, off, 64);
    if (lane == 0) out[b * 10 + c] = s + bc[c];
  }
}

// ================================================================ launch
extern "C" void kernel_launch(void* const* d_in, const int* in_sizes, int n_in,
                              void* d_out, int out_size, void* d_ws, size_t ws_size,
                              hipStream_t stream) {
  const float* features = (const float*)d_in[0];
  const int*   esrc     = (const int*)d_in[1];
  const int*   edst     = (const int*)d_in[2];
  const int*   gid      = (const int*)d_in[3];
  const float* W1 = (const float*)d_in[5];
  const float* b1 = (const float*)d_in[6];
  const float* W2 = (const float*)d_in[7];
  const float* b2 = (const float*)d_in[8];
  const float* cw = (const float*)d_in[9];
  const float* cb = (const float*)d_in[10];
  const float* Wc = (const float*)d_in[11];
  const float* bc = (const float*)d_in[12];
  float* out = (float*)d_out;

  const int N = in_sizes[0] / 64;
  const int E = in_sizes[1];
  const int B = out_size / 10;
  const size_t N64 = (size_t)N * 64;
  const int nscan = (N + 2047) / 2048;       // <= 64 for N <= 131072
  const int P = (N + PART - 1) / PART;       // node partitions

  // workspace carve-up (~58 MB)
  // hist (2*P*MCH*PART ints ~ 28.9 MB) ALIASES bufA/bufB: it is fully
  // consumed by k_fill2 before gemm/gather first write bufA/bufB.
  float* bufA   = (float*)d_ws;            // N*64 : m1 -> m2
  float* bufB   = bufA + N64;              // N*64 : h1 -> h2
  int*   hist   = (int*)d_ws;              // 2*P*MCH*PART (alias)
  int*   deg_d  = (int*)(bufB + N64);      // N
  float* norm_s = (float*)(deg_d + N);     // N
  float* norm_d = norm_s + N;              // N
  float* key    = norm_d + N;              // N
  int*   rowptr = (int*)(key + N);         // N
  int*   csr    = rowptr + N;              // E
  int*   bsum   = csr + E;                 // nscan
  int*   gstart = bsum + nscan;            // B
  int*   gcnt   = gstart + B;              // B
  int*   sel    = gcnt + B;                // 3B
  float* p      = (float*)(sel + 3 * B);   // 192B

  const int TB = 256;

  // ---- CSR build (no global atomics)
  k_hist<<<2 * P * MCH, TB, 0, stream>>>(esrc, edst, hist, N, E, P);
  k_degsum<<<(N + TB - 1) / TB, TB, 0, stream>>>(hist, deg_d, norm_s, norm_d, N, P);
  k_scan1<<<nscan, 256, 0, stream>>>(deg_d, rowptr, bsum, N);
  k_scan2<<<1, 64, 0, stream>>>(bsum, nscan);
  k_scan3b<<<(N + TB - 1) / TB, TB, 0, stream>>>(rowptr, bsum, hist, N, P);
  k_fill2<<<P * MCH, TB, 0, stream>>>(esrc, edst, hist, csr, N, E, P);

  // ---- layer 1
  k_gemm64<<<1024, TB, 0, stream>>>(features, norm_s, W1, bufA, N);
  k_gather<<<(N + 3) / 4, TB, 0, stream>>>(bufA, rowptr, deg_d, norm_d, b1, csr,
                                           bufB, nullptr, N);

  // ---- layer 2 (key = row max fused)
  k_gemm64<<<1024, TB, 0, stream>>>(bufB, norm_s, W2, bufA, N);
  k_gather<<<(N + 3) / 4, TB, 0, stream>>>(bufA, rowptr, deg_d, norm_d, b2, csr,
                                           bufB, key, N);

  // ---- sort-pool (boundary detection on sorted gid; no atomics)
  k_init_starts<<<(B + TB - 1) / TB, TB, 0, stream>>>(gstart, B, N);
  k_bstart<<<(N + TB - 1) / TB, TB, 0, stream>>>(gid, gstart, N);
  k_bfin<<<1, 512, 0, stream>>>(gstart, gcnt, B, N);
  k_top3<<<(B + 3) / 4, TB, 0, stream>>>(key, gstart, gcnt, sel, B);
  k_pool<<<(B * 3 + 3) / 4, TB, 0, stream>>>(bufB, sel, p, B);

  // ---- classifier
  k_cls<<<B, 64, 0, stream>>>(p, cw, cb, Wc, bc, out, B);
}